// Round 1
// baseline (154.724 us; speedup 1.0000x reference)
//
#include <hip/hip_runtime.h>
#include <math.h>

#define BB 8
#define NN 256
#define DD 128
#define HH 256
#define LN_EPS 1e-5f

__device__ __forceinline__ float gelu_exact(float x) {
    // jax.nn.gelu(approximate=False): x * 0.5 * (1 + erf(x / sqrt(2)))
    return 0.5f * x * (1.0f + erff(x * 0.70710678118654752f));
}

// Kernel 1: hi = slots @ W_m1[:D] + b_m1 ; hj = slots @ W_m1[D:]
// grid = B*N blocks, 512 threads (half 0 -> hi, half 1 -> hj)
__global__ __launch_bounds__(512) void k_proj_m1(
    const float* __restrict__ slots, const float* __restrict__ W_m1,
    const float* __restrict__ b_m1, float* __restrict__ hi, float* __restrict__ hj)
{
    __shared__ float s[DD];
    const int row = blockIdx.x;          // b*N + n
    const int t = threadIdx.x;
    const int half = t >> 8;             // 0 => hi (sender), 1 => hj (receiver)
    const int h = t & (HH - 1);
    if (t < DD) s[t] = slots[row * DD + t];
    __syncthreads();
    const float* W = W_m1 + half * DD * HH + h;
    float acc = half ? 0.0f : b_m1[h];   // fold b_m1 into hi once
    #pragma unroll 8
    for (int d = 0; d < DD; ++d) acc += s[d] * W[d * HH];
    float* dst = half ? hj : hi;
    dst[row * HH + h] = acc;
}

// Kernel 2 (hot): g[b,i,h] = sum_j A[b,i,j] * gelu(hi[b,i,h] + hj[b,j,h])
//                 asum[b,i] = sum_j A[b,i,j]
// grid = B*N blocks, 256 threads (thread = h)
__global__ __launch_bounds__(256) void k_msg_agg(
    const float* __restrict__ adj, const float* __restrict__ hi,
    const float* __restrict__ hj, float* __restrict__ g, float* __restrict__ asum)
{
    __shared__ float A[NN];
    __shared__ float red[4];
    const int row = blockIdx.x;          // b*N + i
    const int b = row >> 8;
    const int t = threadIdx.x;           // h index
    float a = adj[row * NN + t];
    A[t] = a;
    // reduce adjacency-row sum (for the b_m2 term)
    float s1 = a;
    #pragma unroll
    for (int o = 32; o > 0; o >>= 1) s1 += __shfl_down(s1, o, 64);
    if ((t & 63) == 0) red[t >> 6] = s1;
    __syncthreads();
    if (t == 0) asum[row] = red[0] + red[1] + red[2] + red[3];

    const float hv = hi[row * HH + t];
    const float* __restrict__ hjb = hj + b * NN * HH + t;
    float acc = 0.0f;
    #pragma unroll 4
    for (int j = 0; j < NN; ++j) {
        float x = hv + hjb[j * HH];
        acc += A[j] * gelu_exact(x);
    }
    g[row * HH + t] = acc;
}

// Kernel 3: aggregated = g @ W_m2 + asum*b_m2 ; u = slots@W_u1[:D] + agg@W_u1[D:] + b_u1
//           u = gelu(LN(u)) ; out = slots + u @ W_u2 + b_u2
// grid = B*N blocks, 256 threads (thread = h for the H-dim phases, t<128 for D-dim phases)
__global__ __launch_bounds__(256) void k_update(
    const float* __restrict__ slots, const float* __restrict__ g,
    const float* __restrict__ asum,
    const float* __restrict__ W_m2, const float* __restrict__ b_m2,
    const float* __restrict__ W_u1, const float* __restrict__ b_u1,
    const float* __restrict__ ln_g, const float* __restrict__ ln_b,
    const float* __restrict__ W_u2, const float* __restrict__ b_u2,
    float* __restrict__ out)
{
    __shared__ float gl[HH];
    __shared__ float sl[DD];
    __shared__ float aggl[DD];
    __shared__ float ul[HH];
    __shared__ float red1[4], red2[4];
    const int row = blockIdx.x;
    const int t = threadIdx.x;
    gl[t] = g[row * HH + t];
    if (t < DD) sl[t] = slots[row * DD + t];
    __syncthreads();
    if (t < DD) {
        float acc = asum[row] * b_m2[t];
        #pragma unroll 8
        for (int h = 0; h < HH; ++h) acc += gl[h] * W_m2[h * DD + t];
        aggl[t] = acc;
    }
    __syncthreads();
    float u = b_u1[t];
    #pragma unroll 8
    for (int d = 0; d < DD; ++d) u += sl[d] * W_u1[d * HH + t];
    #pragma unroll 8
    for (int d = 0; d < DD; ++d) u += aggl[d] * W_u1[(DD + d) * HH + t];
    // LayerNorm over H=256 (4 waves)
    float s1 = u, s2 = u * u;
    #pragma unroll
    for (int o = 32; o > 0; o >>= 1) {
        s1 += __shfl_down(s1, o, 64);
        s2 += __shfl_down(s2, o, 64);
    }
    if ((t & 63) == 0) { red1[t >> 6] = s1; red2[t >> 6] = s2; }
    __syncthreads();
    const float tot1 = red1[0] + red1[1] + red1[2] + red1[3];
    const float tot2 = red2[0] + red2[1] + red2[2] + red2[3];
    const float mu = tot1 * (1.0f / HH);
    const float var = tot2 * (1.0f / HH) - mu * mu;
    const float un = (u - mu) * rsqrtf(var + LN_EPS) * ln_g[t] + ln_b[t];
    ul[t] = gelu_exact(un);
    __syncthreads();
    if (t < DD) {
        float acc = b_u2[t];
        #pragma unroll 8
        for (int h = 0; h < HH; ++h) acc += ul[h] * W_u2[h * DD + t];
        out[row * DD + t] = sl[t] + acc;
    }
}

extern "C" void kernel_launch(void* const* d_in, const int* in_sizes, int n_in,
                              void* d_out, int out_size, void* d_ws, size_t ws_size,
                              hipStream_t stream) {
    const float* slots = (const float*)d_in[0];
    const float* adj   = (const float*)d_in[1];
    const float* W_m1  = (const float*)d_in[2];
    const float* b_m1  = (const float*)d_in[3];
    const float* W_m2  = (const float*)d_in[4];
    const float* b_m2  = (const float*)d_in[5];
    const float* W_u1  = (const float*)d_in[6];
    const float* b_u1  = (const float*)d_in[7];
    const float* ln_g  = (const float*)d_in[8];
    const float* ln_b  = (const float*)d_in[9];
    const float* W_u2  = (const float*)d_in[10];
    const float* b_u2  = (const float*)d_in[11];
    float* out = (float*)d_out;
    float* ws  = (float*)d_ws;

    const int rows = BB * NN;            // 2048
    float* hi   = ws;                    // rows*HH
    float* hj   = hi + (size_t)rows * HH;
    float* g    = hj + (size_t)rows * HH;
    float* asum = g  + (size_t)rows * HH;  // rows

    hipLaunchKernelGGL(k_proj_m1, dim3(rows), dim3(512), 0, stream,
                       slots, W_m1, b_m1, hi, hj);
    hipLaunchKernelGGL(k_msg_agg, dim3(rows), dim3(256), 0, stream,
                       adj, hi, hj, g, asum);
    hipLaunchKernelGGL(k_update, dim3(rows), dim3(256), 0, stream,
                       slots, g, asum, W_m2, b_m2, W_u1, b_u1,
                       ln_g, ln_b, W_u2, b_u2, out);
}

// Round 2
// 121.550 us; speedup vs baseline: 1.2729x; 1.2729x over previous
//
#include <hip/hip_runtime.h>
#include <math.h>

#define BB 8
#define NN 256
#define DD 128
#define HH 256
#define RPB 8            // rows per block for the GEMM-ish kernels
#define LN_EPS 1e-5f

// Branch-free exact-gelu via Abramowitz-Stegun 7.1.26 erf (|err|<=1.5e-7).
// gelu(x) = 0.5x(1+erf(x/sqrt2)) = hx + |hx|*erf(|x|/sqrt2), hx = 0.5x.
__device__ __forceinline__ float gelu_fast(float x) {
    const float z  = fabsf(x) * 0.70710678118654752f;
    const float t  = __builtin_amdgcn_rcpf(fmaf(z, 0.3275911f, 1.0f));
    const float e  = __builtin_amdgcn_exp2f(z * z * -1.4426950408889634f);
    float p = fmaf(t, 1.061405429f, -1.453152027f);
    p = fmaf(t, p, 1.421413741f);
    p = fmaf(t, p, -0.284496736f);
    p = fmaf(t, p, 0.254829592f);
    const float erf_abs = fmaf(-p * t, e, 1.0f);   // erf(|x|/sqrt2)
    const float hx = 0.5f * x;
    return fmaf(fabsf(hx), erf_abs, hx);
}

// Kernel 1: hi = slots @ W_m1[:D] + b_m1 ; hj = slots @ W_m1[D:]
// 8 rows per block; 256 blocks x 256 threads; thread t owns column h=t for
// both halves across all 8 rows (16 accumulators).
__global__ __launch_bounds__(256) void k_proj_m1(
    const float* __restrict__ slots, const float* __restrict__ W_m1,
    const float* __restrict__ b_m1, float* __restrict__ hi, float* __restrict__ hj)
{
    __shared__ __align__(16) float s[DD][RPB];
    const int t = threadIdx.x;
    const int row0 = blockIdx.x * RPB;
    for (int k = t; k < RPB * DD; k += 256) {
        const int r = k >> 7, d = k & (DD - 1);
        s[d][r] = slots[(row0 + r) * DD + d];
    }
    __syncthreads();
    float ai[RPB], aj[RPB];
    const float bm = b_m1[t];
    #pragma unroll
    for (int r = 0; r < RPB; ++r) { ai[r] = bm; aj[r] = 0.0f; }
    const float* __restrict__ Wi = W_m1 + t;
    const float* __restrict__ Wj = W_m1 + DD * HH + t;
    #pragma unroll 4
    for (int d = 0; d < DD; ++d) {
        const float wi = Wi[d * HH];
        const float wj = Wj[d * HH];
        const float4* srow = (const float4*)&s[d][0];
        const float4 s0 = srow[0], s1 = srow[1];
        ai[0] = fmaf(s0.x, wi, ai[0]); aj[0] = fmaf(s0.x, wj, aj[0]);
        ai[1] = fmaf(s0.y, wi, ai[1]); aj[1] = fmaf(s0.y, wj, aj[1]);
        ai[2] = fmaf(s0.z, wi, ai[2]); aj[2] = fmaf(s0.z, wj, aj[2]);
        ai[3] = fmaf(s0.w, wi, ai[3]); aj[3] = fmaf(s0.w, wj, aj[3]);
        ai[4] = fmaf(s1.x, wi, ai[4]); aj[4] = fmaf(s1.x, wj, aj[4]);
        ai[5] = fmaf(s1.y, wi, ai[5]); aj[5] = fmaf(s1.y, wj, aj[5]);
        ai[6] = fmaf(s1.z, wi, ai[6]); aj[6] = fmaf(s1.z, wj, aj[6]);
        ai[7] = fmaf(s1.w, wi, ai[7]); aj[7] = fmaf(s1.w, wj, aj[7]);
    }
    #pragma unroll
    for (int r = 0; r < RPB; ++r) {
        hi[(row0 + r) * HH + t] = ai[r];
        hj[(row0 + r) * HH + t] = aj[r];
    }
}

// Kernel 2 (hot): g[b,i,h] = sum_j A[b,i,j] * gelu(hi[b,i,h] + hj[b,j,h])
//                 asum[b,i] = sum_j A[b,i,j]
__global__ __launch_bounds__(256) void k_msg_agg(
    const float* __restrict__ adj, const float* __restrict__ hi,
    const float* __restrict__ hj, float* __restrict__ g, float* __restrict__ asum)
{
    __shared__ float A[NN];
    __shared__ float red[4];
    const int row = blockIdx.x;          // b*N + i
    const int b = row >> 8;
    const int t = threadIdx.x;           // h index
    const float a = adj[row * NN + t];
    A[t] = a;
    float s1 = a;
    #pragma unroll
    for (int o = 32; o > 0; o >>= 1) s1 += __shfl_down(s1, o, 64);
    if ((t & 63) == 0) red[t >> 6] = s1;
    __syncthreads();
    if (t == 0) asum[row] = red[0] + red[1] + red[2] + red[3];

    const float hv = hi[row * HH + t];
    const float* __restrict__ hjb = hj + b * NN * HH + t;
    float acc = 0.0f;
    #pragma unroll 4
    for (int j = 0; j < NN; ++j)
        acc = fmaf(A[j], gelu_fast(hv + hjb[j * HH]), acc);
    g[row * HH + t] = acc;
}

// Kernel 3: aggregated = g @ W_m2 + asum*b_m2 ; u = slots@W_u1[:D] + agg@W_u1[D:] + b_u1
//           u = gelu(LN(u)) ; out = slots + u @ W_u2 + b_u2
// 8 rows per block; 256 blocks x 256 threads.
__global__ __launch_bounds__(256) void k_update(
    const float* __restrict__ slots, const float* __restrict__ g,
    const float* __restrict__ asum,
    const float* __restrict__ W_m2, const float* __restrict__ b_m2,
    const float* __restrict__ W_u1, const float* __restrict__ b_u1,
    const float* __restrict__ ln_g, const float* __restrict__ ln_b,
    const float* __restrict__ W_u2, const float* __restrict__ b_u2,
    float* __restrict__ out)
{
    __shared__ __align__(16) float gl[HH][RPB];   // 8 KB
    __shared__ __align__(16) float sl[DD][RPB];   // 4 KB
    __shared__ __align__(16) float ag[DD][RPB];   // 4 KB
    __shared__ __align__(16) float ul[HH][RPB];   // 8 KB
    __shared__ float red[RPB][4][2];
    const int t = threadIdx.x;
    const int row0 = blockIdx.x * RPB;

    for (int k = t; k < RPB * HH; k += 256) {
        const int r = k >> 8, h = k & (HH - 1);
        gl[h][r] = g[(row0 + r) * HH + h];
    }
    for (int k = t; k < RPB * DD; k += 256) {
        const int r = k >> 7, d = k & (DD - 1);
        sl[d][r] = slots[(row0 + r) * DD + d];
    }
    __syncthreads();

    // Phase A: aggregated[r][d] = asum[r]*b_m2[d] + sum_h g[r][h]*W_m2[h][d]
    {
        const int d = t & (DD - 1);
        const int rg = (t >> 7) * 4;     // rows rg..rg+3
        float acc[4];
        const float bm = b_m2[d];
        #pragma unroll
        for (int k = 0; k < 4; ++k) acc[k] = asum[row0 + rg + k] * bm;
        const float* __restrict__ W = W_m2 + d;
        #pragma unroll 4
        for (int h = 0; h < HH; ++h) {
            const float w = W[h * DD];
            const float4 gv = *(const float4*)&gl[h][rg];
            acc[0] = fmaf(gv.x, w, acc[0]);
            acc[1] = fmaf(gv.y, w, acc[1]);
            acc[2] = fmaf(gv.z, w, acc[2]);
            acc[3] = fmaf(gv.w, w, acc[3]);
        }
        #pragma unroll
        for (int k = 0; k < 4; ++k) ag[d][rg + k] = acc[k];
    }
    __syncthreads();

    // Phase B: u[r][h=t] = b_u1 + slots@W_u1[:D] + agg@W_u1[D:]
    float u[RPB];
    {
        const float bu = b_u1[t];
        #pragma unroll
        for (int r = 0; r < RPB; ++r) u[r] = bu;
        const float* __restrict__ W1 = W_u1 + t;
        const float* __restrict__ W2 = W_u1 + DD * HH + t;
        #pragma unroll 2
        for (int d = 0; d < DD; ++d) {
            const float w1 = W1[d * HH];
            const float w2 = W2[d * HH];
            const float4* sr = (const float4*)&sl[d][0];
            const float4* ar = (const float4*)&ag[d][0];
            const float4 s0 = sr[0], s1v = sr[1];
            const float4 a0 = ar[0], a1v = ar[1];
            u[0] = fmaf(s0.x, w1, u[0]);  u[0] = fmaf(a0.x, w2, u[0]);
            u[1] = fmaf(s0.y, w1, u[1]);  u[1] = fmaf(a0.y, w2, u[1]);
            u[2] = fmaf(s0.z, w1, u[2]);  u[2] = fmaf(a0.z, w2, u[2]);
            u[3] = fmaf(s0.w, w1, u[3]);  u[3] = fmaf(a0.w, w2, u[3]);
            u[4] = fmaf(s1v.x, w1, u[4]); u[4] = fmaf(a1v.x, w2, u[4]);
            u[5] = fmaf(s1v.y, w1, u[5]); u[5] = fmaf(a1v.y, w2, u[5]);
            u[6] = fmaf(s1v.z, w1, u[6]); u[6] = fmaf(a1v.z, w2, u[6]);
            u[7] = fmaf(s1v.w, w1, u[7]); u[7] = fmaf(a1v.w, w2, u[7]);
        }
    }

    // Phase C: LayerNorm over h (across threads) per row r, then gelu.
    #pragma unroll
    for (int r = 0; r < RPB; ++r) {
        float p1 = u[r], p2 = u[r] * u[r];
        #pragma unroll
        for (int o = 32; o > 0; o >>= 1) {
            p1 += __shfl_xor(p1, o, 64);
            p2 += __shfl_xor(p2, o, 64);
        }
        if ((t & 63) == 0) { red[r][t >> 6][0] = p1; red[r][t >> 6][1] = p2; }
    }
    __syncthreads();
    {
        const float lgv = ln_g[t], lbv = ln_b[t];
        #pragma unroll
        for (int r = 0; r < RPB; ++r) {
            const float tot1 = red[r][0][0] + red[r][1][0] + red[r][2][0] + red[r][3][0];
            const float tot2 = red[r][0][1] + red[r][1][1] + red[r][2][1] + red[r][3][1];
            const float mu = tot1 * (1.0f / HH);
            const float var = tot2 * (1.0f / HH) - mu * mu;
            const float un = (u[r] - mu) * rsqrtf(var + LN_EPS) * lgv + lbv;
            ul[t][r] = gelu_fast(un);
        }
    }
    __syncthreads();

    // Phase D: out[r][d] = slots[r][d] + b_u2[d] + sum_h ul[h][r]*W_u2[h][d]
    {
        const int d = t & (DD - 1);
        const int rg = (t >> 7) * 4;
        float acc[4];
        const float bu = b_u2[d];
        #pragma unroll
        for (int k = 0; k < 4; ++k) acc[k] = bu;
        const float* __restrict__ W = W_u2 + d;
        #pragma unroll 4
        for (int h = 0; h < HH; ++h) {
            const float w = W[h * DD];
            const float4 uv = *(const float4*)&ul[h][rg];
            acc[0] = fmaf(uv.x, w, acc[0]);
            acc[1] = fmaf(uv.y, w, acc[1]);
            acc[2] = fmaf(uv.z, w, acc[2]);
            acc[3] = fmaf(uv.w, w, acc[3]);
        }
        #pragma unroll
        for (int k = 0; k < 4; ++k)
            out[(row0 + rg + k) * DD + d] = sl[d][rg + k] + acc[k];
    }
}

extern "C" void kernel_launch(void* const* d_in, const int* in_sizes, int n_in,
                              void* d_out, int out_size, void* d_ws, size_t ws_size,
                              hipStream_t stream) {
    const float* slots = (const float*)d_in[0];
    const float* adj   = (const float*)d_in[1];
    const float* W_m1  = (const float*)d_in[2];
    const float* b_m1  = (const float*)d_in[3];
    const float* W_m2  = (const float*)d_in[4];
    const float* b_m2  = (const float*)d_in[5];
    const float* W_u1  = (const float*)d_in[6];
    const float* b_u1  = (const float*)d_in[7];
    const float* ln_g  = (const float*)d_in[8];
    const float* ln_b  = (const float*)d_in[9];
    const float* W_u2  = (const float*)d_in[10];
    const float* b_u2  = (const float*)d_in[11];
    float* out = (float*)d_out;
    float* ws  = (float*)d_ws;

    const int rows = BB * NN;            // 2048
    float* hi   = ws;                    // rows*HH
    float* hj   = hi + (size_t)rows * HH;
    float* g    = hj + (size_t)rows * HH;
    float* asum = g  + (size_t)rows * HH;  // rows

    hipLaunchKernelGGL(k_proj_m1, dim3(rows / RPB), dim3(256), 0, stream,
                       slots, W_m1, b_m1, hi, hj);
    hipLaunchKernelGGL(k_msg_agg, dim3(rows), dim3(256), 0, stream,
                       adj, hi, hj, g, asum);
    hipLaunchKernelGGL(k_update, dim3(rows / RPB), dim3(256), 0, stream,
                       slots, g, asum, W_m2, b_m2, W_u1, b_u1,
                       ln_g, ln_b, W_u2, b_u2, out);
}

// Round 3
// 105.997 us; speedup vs baseline: 1.4597x; 1.1467x over previous
//
#include <hip/hip_runtime.h>
#include <math.h>

#define BB 8
#define NN 256
#define DD 128
#define HH 256
#define RPB 8
#define LN_EPS 1e-5f

// Branch-free exact-gelu via Abramowitz-Stegun 7.1.26 erf (|err|<=1.5e-7).
__device__ __forceinline__ float gelu_fast(float x) {
    const float z  = fabsf(x) * 0.70710678118654752f;
    const float t  = __builtin_amdgcn_rcpf(fmaf(z, 0.3275911f, 1.0f));
    const float e  = __builtin_amdgcn_exp2f(z * z * -1.4426950408889634f);
    float p = fmaf(t, 1.061405429f, -1.453152027f);
    p = fmaf(t, p, 1.421413741f);
    p = fmaf(t, p, -0.284496736f);
    p = fmaf(t, p, 0.254829592f);
    const float erf_abs = fmaf(-p * t, e, 1.0f);
    const float hx = 0.5f * x;
    return fmaf(fabsf(hx), erf_abs, hx);
}

// Kernel 1: hi = slots @ W_m1[:D] + b_m1 ; hj = slots @ W_m1[D:]
// grid = 512: (row-group, half). 8 rows per block, 256 threads, 8 accs.
__global__ __launch_bounds__(256) void k_proj_m1(
    const float* __restrict__ slots, const float* __restrict__ W_m1,
    const float* __restrict__ b_m1, float* __restrict__ hi, float* __restrict__ hj)
{
    __shared__ __align__(16) float s[DD][RPB];
    const int t = threadIdx.x;
    const int half = blockIdx.x & 1;
    const int row0 = (blockIdx.x >> 1) * RPB;
    for (int k = t; k < RPB * DD; k += 256) {
        const int r = k & 7, d = k >> 3;           // LDS word = k: conflict-free
        s[d][r] = slots[(row0 + r) * DD + d];
    }
    __syncthreads();
    float acc[RPB];
    const float init = half ? 0.0f : b_m1[t];
    #pragma unroll
    for (int r = 0; r < RPB; ++r) acc[r] = init;
    const float* __restrict__ W = W_m1 + half * DD * HH + t;
    #pragma unroll 4
    for (int d = 0; d < DD; ++d) {
        const float w = W[d * HH];
        const float4* srow = (const float4*)&s[d][0];
        const float4 s0 = srow[0], s1 = srow[1];
        acc[0] = fmaf(s0.x, w, acc[0]);
        acc[1] = fmaf(s0.y, w, acc[1]);
        acc[2] = fmaf(s0.z, w, acc[2]);
        acc[3] = fmaf(s0.w, w, acc[3]);
        acc[4] = fmaf(s1.x, w, acc[4]);
        acc[5] = fmaf(s1.y, w, acc[5]);
        acc[6] = fmaf(s1.z, w, acc[6]);
        acc[7] = fmaf(s1.w, w, acc[7]);
    }
    float* __restrict__ dst = half ? hj : hi;
    #pragma unroll
    for (int r = 0; r < RPB; ++r) dst[(row0 + r) * HH + t] = acc[r];
}

// Kernel 2 (hot): g[b,i,h] = sum_j A[b,i,j]*gelu(hi[b,i,h]+hj[b,j,h]); asum[b,i]=sum_j A
// 4 i-rows per block, 512 threads: h = t&255, j-half = t>>8. 512 blocks.
__global__ __launch_bounds__(512) void k_msg_agg(
    const float* __restrict__ adj, const float* __restrict__ hi,
    const float* __restrict__ hj, float* __restrict__ g, float* __restrict__ asum)
{
    __shared__ __align__(16) float At[NN][4];   // A transposed, 4KB
    __shared__ float pg[4][HH];                 // upper-half partials, 4KB
    const int t = threadIdx.x;
    const int h = t & (HH - 1);
    const int half = t >> 8;
    const int row0 = blockIdx.x * 4;
    const int b = row0 >> 8;
    for (int k = t; k < 4 * NN; k += 512) {
        const int r = k & 3, j = k >> 2;        // LDS word = k: conflict-free
        At[j][r] = adj[(row0 + r) * NN + j];
    }
    __syncthreads();
    if (half == 0) {                            // waves 0-3: adjacency row sums
        const int r = (t >> 6) & 3;
        const int l = t & 63;
        float s1 = At[l][r] + At[l + 64][r] + At[l + 128][r] + At[l + 192][r];
        #pragma unroll
        for (int o = 32; o > 0; o >>= 1) s1 += __shfl_down(s1, o, 64);
        if (l == 0) asum[row0 + r] = s1;
    }
    const float hv0 = hi[(row0 + 0) * HH + h];
    const float hv1 = hi[(row0 + 1) * HH + h];
    const float hv2 = hi[(row0 + 2) * HH + h];
    const float hv3 = hi[(row0 + 3) * HH + h];
    const float* __restrict__ hjb = hj + (size_t)b * NN * HH + half * 128 * HH + h;
    const float* __restrict__ Ab = &At[half * 128][0];
    float a0 = 0.0f, a1 = 0.0f, a2 = 0.0f, a3 = 0.0f;
    #pragma unroll 4
    for (int j = 0; j < 128; ++j) {
        const float hjv = hjb[j * HH];
        const float4 a = *(const float4*)(Ab + j * 4);   // broadcast read
        a0 = fmaf(a.x, gelu_fast(hv0 + hjv), a0);
        a1 = fmaf(a.y, gelu_fast(hv1 + hjv), a1);
        a2 = fmaf(a.z, gelu_fast(hv2 + hjv), a2);
        a3 = fmaf(a.w, gelu_fast(hv3 + hjv), a3);
    }
    if (half) {
        pg[0][h] = a0; pg[1][h] = a1; pg[2][h] = a2; pg[3][h] = a3;
    }
    __syncthreads();
    if (!half) {
        g[(row0 + 0) * HH + h] = a0 + pg[0][h];
        g[(row0 + 1) * HH + h] = a1 + pg[1][h];
        g[(row0 + 2) * HH + h] = a2 + pg[2][h];
        g[(row0 + 3) * HH + h] = a3 + pg[3][h];
    }
}

// Kernel 3: ag = g@W_m2 + asum*b_m2 ; u = sl@W_u1[:D] + ag@W_u1[D:] + b_u1
//           u = gelu(LN(u)) ; out = slots + u@W_u2 + b_u2
// 1024 threads, 8 rows per block, 256 blocks (16 waves/CU).
__global__ __launch_bounds__(1024) void k_update(
    const float* __restrict__ slots, const float* __restrict__ g,
    const float* __restrict__ asum,
    const float* __restrict__ W_m2, const float* __restrict__ b_m2,
    const float* __restrict__ W_u1, const float* __restrict__ b_u1,
    const float* __restrict__ ln_g, const float* __restrict__ ln_b,
    const float* __restrict__ W_u2, const float* __restrict__ b_u2,
    float* __restrict__ out)
{
    __shared__ float gl[HH][RPB];        // 8KB   gl[h][r]
    __shared__ float sl[DD][RPB];        // 4KB
    __shared__ float ag[DD][RPB];        // 4KB
    __shared__ float ul[HH][9];          // 9KB, stride 9 (gcd(9,32)=1: conflict-free)
    __shared__ float4 red[4][4];
    const int t = threadIdx.x;
    const int row0 = blockIdx.x * RPB;

    for (int k = t; k < RPB * HH; k += 1024) {
        const int r = k & 7, hh = k >> 3;          // LDS word = k
        gl[hh][r] = g[(row0 + r) * HH + hh];
    }
    for (int k = t; k < RPB * DD; k += 1024) {
        const int r = k & 7, d = k >> 3;
        sl[d][r] = slots[(row0 + r) * DD + d];
    }
    __syncthreads();

    // Phase A: ag[d][r], t = d + 128*r
    {
        const int d = t & (DD - 1), r = t >> 7;
        float acc = asum[row0 + r] * b_m2[d];
        const float* __restrict__ W = W_m2 + d;
        #pragma unroll 8
        for (int hh = 0; hh < HH; ++hh) acc = fmaf(gl[hh][r], W[hh * DD], acc);
        ag[d][r] = acc;
    }
    __syncthreads();

    // Phase B: u for rows 2*rg, 2*rg+1;  t = h + 256*rg
    const int h = t & (HH - 1), rg = t >> 8;
    float u0 = b_u1[h], u1 = u0;
    {
        const float* __restrict__ W1 = W_u1 + h;
        const float* __restrict__ W2 = W_u1 + DD * HH + h;
        #pragma unroll 4
        for (int d = 0; d < DD; ++d) {
            const float w1 = W1[d * HH];
            const float w2 = W2[d * HH];
            const float2 sv = *(const float2*)&sl[d][2 * rg];   // broadcast
            const float2 av = *(const float2*)&ag[d][2 * rg];
            u0 = fmaf(sv.x, w1, u0); u0 = fmaf(av.x, w2, u0);
            u1 = fmaf(sv.y, w1, u1); u1 = fmaf(av.y, w2, u1);
        }
    }

    // Phase C: LayerNorm over h per row, then gelu -> ul
    {
        float s1a = u0, s2a = u0 * u0, s1b = u1, s2b = u1 * u1;
        #pragma unroll
        for (int o = 32; o > 0; o >>= 1) {
            s1a += __shfl_xor(s1a, o, 64);
            s2a += __shfl_xor(s2a, o, 64);
            s1b += __shfl_xor(s1b, o, 64);
            s2b += __shfl_xor(s2b, o, 64);
        }
        if ((t & 63) == 0) red[rg][(t >> 6) & 3] = make_float4(s1a, s2a, s1b, s2b);
    }
    __syncthreads();
    {
        const float4 r0 = red[rg][0], r1 = red[rg][1], r2 = red[rg][2], r3 = red[rg][3];
        const float lgv = ln_g[h], lbv = ln_b[h];
        const float t1a = r0.x + r1.x + r2.x + r3.x;
        const float t2a = r0.y + r1.y + r2.y + r3.y;
        const float t1b = r0.z + r1.z + r2.z + r3.z;
        const float t2b = r0.w + r1.w + r2.w + r3.w;
        const float mu0 = t1a * (1.0f / HH);
        const float var0 = t2a * (1.0f / HH) - mu0 * mu0;
        const float mu1 = t1b * (1.0f / HH);
        const float var1 = t2b * (1.0f / HH) - mu1 * mu1;
        ul[h][2 * rg]     = gelu_fast((u0 - mu0) * rsqrtf(var0 + LN_EPS) * lgv + lbv);
        ul[h][2 * rg + 1] = gelu_fast((u1 - mu1) * rsqrtf(var1 + LN_EPS) * lgv + lbv);
    }
    __syncthreads();

    // Phase D: out[r][d] = sl + b_u2 + sum_h ul[h][r]*W_u2[h][d];  t = d + 128*r
    {
        const int d = t & (DD - 1), r = t >> 7;
        float acc = b_u2[d];
        const float* __restrict__ W = W_u2 + d;
        #pragma unroll 8
        for (int hh = 0; hh < HH; ++hh) acc = fmaf(ul[hh][r], W[hh * DD], acc);
        out[(row0 + r) * DD + d] = sl[d][r] + acc;
    }
}

extern "C" void kernel_launch(void* const* d_in, const int* in_sizes, int n_in,
                              void* d_out, int out_size, void* d_ws, size_t ws_size,
                              hipStream_t stream) {
    const float* slots = (const float*)d_in[0];
    const float* adj   = (const float*)d_in[1];
    const float* W_m1  = (const float*)d_in[2];
    const float* b_m1  = (const float*)d_in[3];
    const float* W_m2  = (const float*)d_in[4];
    const float* b_m2  = (const float*)d_in[5];
    const float* W_u1  = (const float*)d_in[6];
    const float* b_u1  = (const float*)d_in[7];
    const float* ln_g  = (const float*)d_in[8];
    const float* ln_b  = (const float*)d_in[9];
    const float* W_u2  = (const float*)d_in[10];
    const float* b_u2  = (const float*)d_in[11];
    float* out = (float*)d_out;
    float* ws  = (float*)d_ws;

    const int rows = BB * NN;            // 2048
    float* hi   = ws;
    float* hj   = hi + (size_t)rows * HH;
    float* g    = hj + (size_t)rows * HH;
    float* asum = g  + (size_t)rows * HH;

    hipLaunchKernelGGL(k_proj_m1, dim3(rows / RPB * 2), dim3(256), 0, stream,
                       slots, W_m1, b_m1, hi, hj);
    hipLaunchKernelGGL(k_msg_agg, dim3(rows / 4), dim3(512), 0, stream,
                       adj, hi, hj, g, asum);
    hipLaunchKernelGGL(k_update, dim3(rows / RPB), dim3(1024), 0, stream,
                       slots, g, asum, W_m2, b_m2, W_u1, b_u1,
                       ln_g, ln_b, W_u2, b_u2, out);
}

// Round 4
// 83.455 us; speedup vs baseline: 1.8540x; 1.2701x over previous
//
#include <hip/hip_runtime.h>
#include <math.h>

#define BB 8
#define NN 256
#define DD 128
#define HH 256
#define LN_EPS 1e-5f

// gelu2(x) = 2*gelu(x) = x + |x|*erf(|x|/sqrt2), branch-free A-S 7.1.26 erf.
// (fold the 0.5 into the consumer's scale factor)
__device__ __forceinline__ float gelu2(float x) {
    const float x2 = x * x;
    const float q  = fmaf(fabsf(x), 0.23164429f, 1.0f);      // 1 + p*|x|/sqrt2
    const float tt = __builtin_amdgcn_rcpf(q);
    const float e  = __builtin_amdgcn_exp2f(x2 * -0.72134752f); // exp(-x^2/2)
    float p = fmaf(tt, 1.061405429f, -1.453152027f);
    p = fmaf(tt, p, 1.421413741f);
    p = fmaf(tt, p, -0.284496736f);
    p = fmaf(tt, p, 0.254829592f);
    const float erf_abs = fmaf(-p * tt, e, 1.0f);
    return fmaf(fabsf(x), erf_abs, x);
}

// Kernel 1: hi = slots @ W_m1[:D] + b_m1 ; hj = slots @ W_m1[D:]
// 4 rows/block, 512 threads (h = t&255, half = t>>8), 512 blocks.
__global__ __launch_bounds__(512, 8) void k_proj_m1(
    const float* __restrict__ slots, const float* __restrict__ W_m1,
    const float* __restrict__ b_m1, float* __restrict__ hi, float* __restrict__ hj)
{
    __shared__ __align__(16) float s[DD][4];
    const int t = threadIdx.x;
    const int h = t & (HH - 1);
    const int half = t >> 8;
    const int row0 = blockIdx.x * 4;
    {   // 512 threads stage 4*128 floats exactly
        const int r = t & 3, d = t >> 2;
        s[d][r] = slots[(row0 + r) * DD + d];
    }
    __syncthreads();
    const float init = half ? 0.0f : b_m1[h];
    float a0 = init, a1 = init, a2 = init, a3 = init;
    const float* __restrict__ W = W_m1 + half * DD * HH + h;
    #pragma unroll 4
    for (int d = 0; d < DD; ++d) {
        const float w = W[d * HH];
        const float4 sv = *(const float4*)&s[d][0];   // broadcast
        a0 = fmaf(sv.x, w, a0);
        a1 = fmaf(sv.y, w, a1);
        a2 = fmaf(sv.z, w, a2);
        a3 = fmaf(sv.w, w, a3);
    }
    float* __restrict__ dst = half ? hj : hi;
    dst[(row0 + 0) * HH + h] = a0;
    dst[(row0 + 1) * HH + h] = a1;
    dst[(row0 + 2) * HH + h] = a2;
    dst[(row0 + 3) * HH + h] = a3;
}

// Kernel 2 (hot): g[b,i,h] = sum_j A[b,i,j]*gelu(hi[b,i,h]+hj[b,j,h]); asum = sum_j A
// 2 rows/block, 512 threads (h = t&255, j-half = t>>8), 1024 blocks = 4/CU (100% occ).
__global__ __launch_bounds__(512, 8) void k_msg_agg(
    const float* __restrict__ adj, const float* __restrict__ hi,
    const float* __restrict__ hj, float* __restrict__ g, float* __restrict__ asum)
{
    __shared__ __align__(16) float At[NN][2];   // 2KB, pre-scaled by 0.5
    __shared__ float pg[2][HH];                 // 2KB
    const int t = threadIdx.x;
    const int h = t & (HH - 1);
    const int half = t >> 8;
    const int row0 = blockIdx.x * 2;
    const int b = row0 >> 8;
    {   // stage 0.5*A transposed; 512 threads cover 2*256 exactly
        const int j = t >> 1, r = t & 1;
        At[j][r] = 0.5f * adj[(row0 + r) * NN + j];
    }
    if (t < 128) {                              // waves 0-1: raw adjacency row sums
        const int r = t >> 6, l = t & 63;
        const float* __restrict__ arow = adj + (row0 + r) * NN;
        float s1 = arow[l] + arow[l + 64] + arow[l + 128] + arow[l + 192];
        #pragma unroll
        for (int o = 32; o > 0; o >>= 1) s1 += __shfl_down(s1, o, 64);
        if (l == 0) asum[row0 + r] = s1;
    }
    __syncthreads();
    const float hv0 = hi[(row0 + 0) * HH + h];
    const float hv1 = hi[(row0 + 1) * HH + h];
    const float* __restrict__ hjb = hj + (size_t)b * NN * HH + half * 128 * HH + h;
    const float2* __restrict__ Arow = (const float2*)&At[half * 128][0];
    float a0 = 0.0f, a1 = 0.0f;
    #pragma unroll 4
    for (int j = 0; j < 128; ++j) {
        const float hjv = hjb[j * HH];
        const float2 a = Arow[j];               // ds_read_b64 broadcast
        a0 = fmaf(a.x, gelu2(hv0 + hjv), a0);
        a1 = fmaf(a.y, gelu2(hv1 + hjv), a1);
    }
    if (half) { pg[0][h] = a0; pg[1][h] = a1; }
    __syncthreads();
    if (!half) {
        g[(row0 + 0) * HH + h] = a0 + pg[0][h];
        g[(row0 + 1) * HH + h] = a1 + pg[1][h];
    }
}

// Kernel 3: ag = g@W_m2 + asum*b_m2 ; u = sl@W_u1[:D] + ag@W_u1[D:] + b_u1
//           u = gelu(LN(u)) ; out = slots + u@W_u2 + b_u2
// 8 rows/block, 1024 threads, 256 blocks. Each matmul phase is chunked so
// every W element is loaded exactly ONCE per block (partials in LDS arena).
__global__ __launch_bounds__(1024, 8) void k_update(
    const float* __restrict__ slots, const float* __restrict__ g,
    const float* __restrict__ asum,
    const float* __restrict__ W_m2, const float* __restrict__ b_m2,
    const float* __restrict__ W_u1, const float* __restrict__ b_u1,
    const float* __restrict__ ln_g, const float* __restrict__ ln_b,
    const float* __restrict__ W_u2, const float* __restrict__ b_u2,
    float* __restrict__ out)
{
    __shared__ __align__(16) float gl[HH][8];   // 8KB  gl[h][r]
    __shared__ __align__(16) float sl[DD][8];   // 4KB
    __shared__ __align__(16) float ag[DD][8];   // 4KB
    __shared__ __align__(16) float ul[HH][10];  // 10KB, stride 10 (b64-aligned rows)
    __shared__ float4 red[4][4];
    __shared__ float arena[9216];               // 36KB: pA[8][128][9] / pB[4][256][9]
    const int t = threadIdx.x;
    const int row0 = blockIdx.x * 8;

    for (int k = t; k < 8 * HH; k += 1024) {
        const int r = k & 7, hh = k >> 3;
        gl[hh][r] = g[(row0 + r) * HH + hh];
    }
    for (int k = t; k < 8 * DD; k += 1024) {
        const int r = k & 7, d = k >> 3;
        sl[d][r] = slots[(row0 + r) * DD + d];
    }
    __syncthreads();

    // Phase A: partial ag over hh-chunk. thread (d = t&127, hc = t>>7), 32 hh each.
    {
        const int d = t & (DD - 1), hc = t >> 7;
        float pa[8] = {0, 0, 0, 0, 0, 0, 0, 0};
        const float* __restrict__ W = W_m2 + d;
        const int hh0 = hc * 32;
        #pragma unroll 4
        for (int hh = hh0; hh < hh0 + 32; ++hh) {
            const float w = W[hh * DD];
            const float4 g0 = *(const float4*)&gl[hh][0];   // broadcast
            const float4 g1 = *(const float4*)&gl[hh][4];
            pa[0] = fmaf(g0.x, w, pa[0]); pa[1] = fmaf(g0.y, w, pa[1]);
            pa[2] = fmaf(g0.z, w, pa[2]); pa[3] = fmaf(g0.w, w, pa[3]);
            pa[4] = fmaf(g1.x, w, pa[4]); pa[5] = fmaf(g1.y, w, pa[5]);
            pa[6] = fmaf(g1.z, w, pa[6]); pa[7] = fmaf(g1.w, w, pa[7]);
        }
        float* pw = arena + hc * (DD * 9) + d * 9;
        #pragma unroll
        for (int r = 0; r < 8; ++r) pw[r] = pa[r];
    }
    __syncthreads();
    {   // combine A: thread (d = t&127, r = t>>7)
        const int d = t & (DD - 1), r = t >> 7;
        float acc = asum[row0 + r] * b_m2[d];
        #pragma unroll
        for (int hc = 0; hc < 8; ++hc) acc += arena[hc * (DD * 9) + d * 9 + r];
        ag[d][r] = acc;
    }
    __syncthreads();

    // Phase B: partial u over d-chunk. thread (h = t&255, dc = t>>8), 32 d each.
    {
        const int h = t & (HH - 1), dc = t >> 8;
        float pu[8] = {0, 0, 0, 0, 0, 0, 0, 0};
        const float* __restrict__ W1 = W_u1 + h;
        const float* __restrict__ W2 = W_u1 + DD * HH + h;
        const int d0 = dc * 32;
        #pragma unroll 2
        for (int d = d0; d < d0 + 32; ++d) {
            const float w1 = W1[d * HH];
            const float w2 = W2[d * HH];
            const float4 s0 = *(const float4*)&sl[d][0];
            const float4 s1 = *(const float4*)&sl[d][4];
            const float4 a0 = *(const float4*)&ag[d][0];
            const float4 a1 = *(const float4*)&ag[d][4];
            pu[0] = fmaf(s0.x, w1, pu[0]); pu[0] = fmaf(a0.x, w2, pu[0]);
            pu[1] = fmaf(s0.y, w1, pu[1]); pu[1] = fmaf(a0.y, w2, pu[1]);
            pu[2] = fmaf(s0.z, w1, pu[2]); pu[2] = fmaf(a0.z, w2, pu[2]);
            pu[3] = fmaf(s0.w, w1, pu[3]); pu[3] = fmaf(a0.w, w2, pu[3]);
            pu[4] = fmaf(s1.x, w1, pu[4]); pu[4] = fmaf(a1.x, w2, pu[4]);
            pu[5] = fmaf(s1.y, w1, pu[5]); pu[5] = fmaf(a1.y, w2, pu[5]);
            pu[6] = fmaf(s1.z, w1, pu[6]); pu[6] = fmaf(a1.z, w2, pu[6]);
            pu[7] = fmaf(s1.w, w1, pu[7]); pu[7] = fmaf(a1.w, w2, pu[7]);
        }
        float* pw = arena + dc * (HH * 9) + h * 9;
        #pragma unroll
        for (int r = 0; r < 8; ++r) pw[r] = pu[r];
    }
    __syncthreads();

    // combine B + LayerNorm + gelu. thread (h = t&255, rg = t>>8) rows {2rg, 2rg+1}.
    const int h = t & (HH - 1), rg = t >> 8;
    {
        float u0 = b_u1[h], u1 = u0;
        #pragma unroll
        for (int dc = 0; dc < 4; ++dc) {
            u0 += arena[dc * (HH * 9) + h * 9 + 2 * rg];
            u1 += arena[dc * (HH * 9) + h * 9 + 2 * rg + 1];
        }
        float s1a = u0, s2a = u0 * u0, s1b = u1, s2b = u1 * u1;
        #pragma unroll
        for (int o = 32; o > 0; o >>= 1) {
            s1a += __shfl_xor(s1a, o, 64);
            s2a += __shfl_xor(s2a, o, 64);
            s1b += __shfl_xor(s1b, o, 64);
            s2b += __shfl_xor(s2b, o, 64);
        }
        if ((t & 63) == 0) red[rg][(t >> 6) & 3] = make_float4(s1a, s2a, s1b, s2b);
        __syncthreads();
        const float4 r0 = red[rg][0], r1 = red[rg][1], r2 = red[rg][2], r3 = red[rg][3];
        const float lgv = ln_g[h], lbv = ln_b[h];
        const float t1a = r0.x + r1.x + r2.x + r3.x;
        const float t2a = r0.y + r1.y + r2.y + r3.y;
        const float t1b = r0.z + r1.z + r2.z + r3.z;
        const float t2b = r0.w + r1.w + r2.w + r3.w;
        const float mu0 = t1a * (1.0f / HH);
        const float var0 = t2a * (1.0f / HH) - mu0 * mu0;
        const float mu1 = t1b * (1.0f / HH);
        const float var1 = t2b * (1.0f / HH) - mu1 * mu1;
        ul[h][2 * rg]     = 0.5f * gelu2((u0 - mu0) * rsqrtf(var0 + LN_EPS) * lgv + lbv);
        ul[h][2 * rg + 1] = 0.5f * gelu2((u1 - mu1) * rsqrtf(var1 + LN_EPS) * lgv + lbv);
    }
    __syncthreads();

    // Phase D: partial out over hh-chunk. thread (d = t&127, hc = t>>7), 32 hh each.
    {
        const int d = t & (DD - 1), hc = t >> 7;
        float pd[8] = {0, 0, 0, 0, 0, 0, 0, 0};
        const float* __restrict__ W = W_u2 + d;
        const int hh0 = hc * 32;
        #pragma unroll 4
        for (int hh = hh0; hh < hh0 + 32; ++hh) {
            const float w = W[hh * DD];
            const float2 u01 = *(const float2*)&ul[hh][0];   // broadcast b64 x4
            const float2 u23 = *(const float2*)&ul[hh][2];
            const float2 u45 = *(const float2*)&ul[hh][4];
            const float2 u67 = *(const float2*)&ul[hh][6];
            pd[0] = fmaf(u01.x, w, pd[0]); pd[1] = fmaf(u01.y, w, pd[1]);
            pd[2] = fmaf(u23.x, w, pd[2]); pd[3] = fmaf(u23.y, w, pd[3]);
            pd[4] = fmaf(u45.x, w, pd[4]); pd[5] = fmaf(u45.y, w, pd[5]);
            pd[6] = fmaf(u67.x, w, pd[6]); pd[7] = fmaf(u67.y, w, pd[7]);
        }
        float* pw = arena + hc * (DD * 9) + d * 9;
        #pragma unroll
        for (int r = 0; r < 8; ++r) pw[r] = pd[r];
    }
    __syncthreads();
    {   // combine D: thread (d = t&127, r = t>>7)
        const int d = t & (DD - 1), r = t >> 7;
        float acc = b_u2[d];
        #pragma unroll
        for (int hc = 0; hc < 8; ++hc) acc += arena[hc * (DD * 9) + d * 9 + r];
        out[(row0 + r) * DD + d] = sl[d][r] + acc;
    }
}

extern "C" void kernel_launch(void* const* d_in, const int* in_sizes, int n_in,
                              void* d_out, int out_size, void* d_ws, size_t ws_size,
                              hipStream_t stream) {
    const float* slots = (const float*)d_in[0];
    const float* adj   = (const float*)d_in[1];
    const float* W_m1  = (const float*)d_in[2];
    const float* b_m1  = (const float*)d_in[3];
    const float* W_m2  = (const float*)d_in[4];
    const float* b_m2  = (const float*)d_in[5];
    const float* W_u1  = (const float*)d_in[6];
    const float* b_u1  = (const float*)d_in[7];
    const float* ln_g  = (const float*)d_in[8];
    const float* ln_b  = (const float*)d_in[9];
    const float* W_u2  = (const float*)d_in[10];
    const float* b_u2  = (const float*)d_in[11];
    float* out = (float*)d_out;
    float* ws  = (float*)d_ws;

    const int rows = BB * NN;            // 2048
    float* hi   = ws;
    float* hj   = hi + (size_t)rows * HH;
    float* g    = hj + (size_t)rows * HH;
    float* asum = g  + (size_t)rows * HH;

    hipLaunchKernelGGL(k_proj_m1, dim3(rows / 4), dim3(512), 0, stream,
                       slots, W_m1, b_m1, hi, hj);
    hipLaunchKernelGGL(k_msg_agg, dim3(rows / 2), dim3(512), 0, stream,
                       adj, hi, hj, g, asum);
    hipLaunchKernelGGL(k_update, dim3(rows / 8), dim3(1024), 0, stream,
                       slots, g, asum, W_m2, b_m2, W_u1, b_u1,
                       ln_g, ln_b, W_u2, b_u2, out);
}

// Round 5
// 81.791 us; speedup vs baseline: 1.8917x; 1.0203x over previous
//
#include <hip/hip_runtime.h>
#include <math.h>

#define BB 8
#define NN 256
#define DD 128
#define HH 256
#define LN_EPS 1e-5f

// gelu2(x) = 2*gelu(x) = x + |x|*erf(|x|/sqrt2), branch-free A-S 7.1.26 erf.
// (fold the 0.5 into the consumer's scale factor)
__device__ __forceinline__ float gelu2(float x) {
    const float x2 = x * x;
    const float q  = fmaf(fabsf(x), 0.23164429f, 1.0f);      // 1 + p*|x|/sqrt2
    const float tt = __builtin_amdgcn_rcpf(q);
    const float e  = __builtin_amdgcn_exp2f(x2 * -0.72134752f); // exp(-x^2/2)
    float p = fmaf(tt, 1.061405429f, -1.453152027f);
    p = fmaf(tt, p, 1.421413741f);
    p = fmaf(tt, p, -0.284496736f);
    p = fmaf(tt, p, 0.254829592f);
    const float erf_abs = fmaf(-p * tt, e, 1.0f);
    return fmaf(fabsf(x), erf_abs, x);
}

// Kernel 1: hi = slots @ W_m1[:D] + b_m1 ; hj = slots @ W_m1[D:]
// 4 rows/block, 512 threads (h = t&255, half = t>>8), 512 blocks.
__global__ __launch_bounds__(512, 8) void k_proj_m1(
    const float* __restrict__ slots, const float* __restrict__ W_m1,
    const float* __restrict__ b_m1, float* __restrict__ hi, float* __restrict__ hj)
{
    __shared__ __align__(16) float s[DD][4];
    const int t = threadIdx.x;
    const int h = t & (HH - 1);
    const int half = t >> 8;
    const int row0 = blockIdx.x * 4;
    {   // 512 threads stage 4*128 floats exactly
        const int r = t & 3, d = t >> 2;
        s[d][r] = slots[(row0 + r) * DD + d];
    }
    __syncthreads();
    const float init = half ? 0.0f : b_m1[h];
    float a0 = init, a1 = init, a2 = init, a3 = init;
    const float* __restrict__ W = W_m1 + half * DD * HH + h;
    #pragma unroll 4
    for (int d = 0; d < DD; ++d) {
        const float w = W[d * HH];
        const float4 sv = *(const float4*)&s[d][0];   // broadcast
        a0 = fmaf(sv.x, w, a0);
        a1 = fmaf(sv.y, w, a1);
        a2 = fmaf(sv.z, w, a2);
        a3 = fmaf(sv.w, w, a3);
    }
    float* __restrict__ dst = half ? hj : hi;
    dst[(row0 + 0) * HH + h] = a0;
    dst[(row0 + 1) * HH + h] = a1;
    dst[(row0 + 2) * HH + h] = a2;
    dst[(row0 + 3) * HH + h] = a3;
}

// Kernel 2 (hot): g[b,i,h] = sum_j A[b,i,j]*gelu(hi[b,i,h]+hj[b,j,h]); asum = sum_j A
// 1 row per block, 2048 blocks x 256 threads (8 blocks/CU = 100% occupancy).
// Thread = (jq = t>>6, h0 = (t&63)*4): b128 hj loads feed 4 gelus each.
__global__ __launch_bounds__(256, 4) void k_msg_agg(
    const float* __restrict__ adj, const float* __restrict__ hi,
    const float* __restrict__ hj, float* __restrict__ g, float* __restrict__ asum)
{
    __shared__ __align__(16) float At[NN];      // 1KB, pre-scaled by 0.5
    __shared__ __align__(16) float pg[3][HH];   // 3KB partials from jq=1..3
    const int t = threadIdx.x;
    const int row = blockIdx.x;
    const int b = row >> 8;
    const int jq = t >> 6;
    const int h0 = (t & 63) * 4;

    At[t] = 0.5f * adj[(size_t)row * NN + t];
    if (t < 64) {                               // wave 0: raw adjacency row sum
        const float* __restrict__ ar = adj + (size_t)row * NN;
        float s1 = ar[t] + ar[t + 64] + ar[t + 128] + ar[t + 192];
        #pragma unroll
        for (int o = 32; o > 0; o >>= 1) s1 += __shfl_down(s1, o, 64);
        if (t == 0) asum[row] = s1;
    }
    __syncthreads();

    const float4 hv = *(const float4*)(hi + (size_t)row * HH + h0);
    const float* __restrict__ hjp = hj + ((size_t)b * NN + jq * 64) * HH + h0;
    const float* __restrict__ Aq = &At[jq * 64];
    float a0 = 0.0f, a1 = 0.0f, a2 = 0.0f, a3 = 0.0f;
    float4 cur = *(const float4*)hjp;
    #pragma unroll 2
    for (int jj = 0; jj < 63; ++jj) {
        const float4 nxt = *(const float4*)(hjp + (size_t)(jj + 1) * HH);  // prefetch
        const float Aj = Aq[jj];                 // ds_read_b32 broadcast
        a0 = fmaf(Aj, gelu2(hv.x + cur.x), a0);
        a1 = fmaf(Aj, gelu2(hv.y + cur.y), a1);
        a2 = fmaf(Aj, gelu2(hv.z + cur.z), a2);
        a3 = fmaf(Aj, gelu2(hv.w + cur.w), a3);
        cur = nxt;
    }
    {
        const float Aj = Aq[63];
        a0 = fmaf(Aj, gelu2(hv.x + cur.x), a0);
        a1 = fmaf(Aj, gelu2(hv.y + cur.y), a1);
        a2 = fmaf(Aj, gelu2(hv.z + cur.z), a2);
        a3 = fmaf(Aj, gelu2(hv.w + cur.w), a3);
    }
    if (jq) *(float4*)&pg[jq - 1][h0] = make_float4(a0, a1, a2, a3);
    __syncthreads();
    if (!jq) {
        const float4 p0 = *(const float4*)&pg[0][h0];
        const float4 p1 = *(const float4*)&pg[1][h0];
        const float4 p2 = *(const float4*)&pg[2][h0];
        *(float4*)(g + (size_t)row * HH + h0) =
            make_float4(a0 + p0.x + p1.x + p2.x, a1 + p0.y + p1.y + p2.y,
                        a2 + p0.z + p1.z + p2.z, a3 + p0.w + p1.w + p2.w);
    }
}

// Kernel 3: ag = g@W_m2 + asum*b_m2 ; u = sl@W_u1[:D] + ag@W_u1[D:] + b_u1
//           u = gelu(LN(u)) ; out = slots + u@W_u2 + b_u2
// 8 rows/block, 1024 threads, 256 blocks. Each matmul phase is chunked so
// every W element is loaded exactly ONCE per block (partials in LDS arena).
__global__ __launch_bounds__(1024, 8) void k_update(
    const float* __restrict__ slots, const float* __restrict__ g,
    const float* __restrict__ asum,
    const float* __restrict__ W_m2, const float* __restrict__ b_m2,
    const float* __restrict__ W_u1, const float* __restrict__ b_u1,
    const float* __restrict__ ln_g, const float* __restrict__ ln_b,
    const float* __restrict__ W_u2, const float* __restrict__ b_u2,
    float* __restrict__ out)
{
    __shared__ __align__(16) float gl[HH][8];   // 8KB  gl[h][r]
    __shared__ __align__(16) float sl[DD][8];   // 4KB
    __shared__ __align__(16) float ag[DD][8];   // 4KB
    __shared__ __align__(16) float ul[HH][10];  // 10KB, stride 10 (b64-aligned rows)
    __shared__ float4 red[4][4];
    __shared__ float arena[9216];               // 36KB: pA[8][128][9] / pB[4][256][9]
    const int t = threadIdx.x;
    const int row0 = blockIdx.x * 8;

    for (int k = t; k < 8 * HH; k += 1024) {
        const int r = k & 7, hh = k >> 3;
        gl[hh][r] = g[(row0 + r) * HH + hh];
    }
    for (int k = t; k < 8 * DD; k += 1024) {
        const int r = k & 7, d = k >> 3;
        sl[d][r] = slots[(row0 + r) * DD + d];
    }
    __syncthreads();

    // Phase A: partial ag over hh-chunk. thread (d = t&127, hc = t>>7), 32 hh each.
    {
        const int d = t & (DD - 1), hc = t >> 7;
        float pa[8] = {0, 0, 0, 0, 0, 0, 0, 0};
        const float* __restrict__ W = W_m2 + d;
        const int hh0 = hc * 32;
        #pragma unroll 4
        for (int hh = hh0; hh < hh0 + 32; ++hh) {
            const float w = W[hh * DD];
            const float4 g0 = *(const float4*)&gl[hh][0];   // broadcast
            const float4 g1 = *(const float4*)&gl[hh][4];
            pa[0] = fmaf(g0.x, w, pa[0]); pa[1] = fmaf(g0.y, w, pa[1]);
            pa[2] = fmaf(g0.z, w, pa[2]); pa[3] = fmaf(g0.w, w, pa[3]);
            pa[4] = fmaf(g1.x, w, pa[4]); pa[5] = fmaf(g1.y, w, pa[5]);
            pa[6] = fmaf(g1.z, w, pa[6]); pa[7] = fmaf(g1.w, w, pa[7]);
        }
        float* pw = arena + hc * (DD * 9) + d * 9;
        #pragma unroll
        for (int r = 0; r < 8; ++r) pw[r] = pa[r];
    }
    __syncthreads();
    {   // combine A: thread (d = t&127, r = t>>7)
        const int d = t & (DD - 1), r = t >> 7;
        float acc = asum[row0 + r] * b_m2[d];
        #pragma unroll
        for (int hc = 0; hc < 8; ++hc) acc += arena[hc * (DD * 9) + d * 9 + r];
        ag[d][r] = acc;
    }
    __syncthreads();

    // Phase B: partial u over d-chunk. thread (h = t&255, dc = t>>8), 32 d each.
    {
        const int h = t & (HH - 1), dc = t >> 8;
        float pu[8] = {0, 0, 0, 0, 0, 0, 0, 0};
        const float* __restrict__ W1 = W_u1 + h;
        const float* __restrict__ W2 = W_u1 + DD * HH + h;
        const int d0 = dc * 32;
        #pragma unroll 2
        for (int d = d0; d < d0 + 32; ++d) {
            const float w1 = W1[d * HH];
            const float w2 = W2[d * HH];
            const float4 s0 = *(const float4*)&sl[d][0];
            const float4 s1 = *(const float4*)&sl[d][4];
            const float4 a0 = *(const float4*)&ag[d][0];
            const float4 a1 = *(const float4*)&ag[d][4];
            pu[0] = fmaf(s0.x, w1, pu[0]); pu[0] = fmaf(a0.x, w2, pu[0]);
            pu[1] = fmaf(s0.y, w1, pu[1]); pu[1] = fmaf(a0.y, w2, pu[1]);
            pu[2] = fmaf(s0.z, w1, pu[2]); pu[2] = fmaf(a0.z, w2, pu[2]);
            pu[3] = fmaf(s0.w, w1, pu[3]); pu[3] = fmaf(a0.w, w2, pu[3]);
            pu[4] = fmaf(s1.x, w1, pu[4]); pu[4] = fmaf(a1.x, w2, pu[4]);
            pu[5] = fmaf(s1.y, w1, pu[5]); pu[5] = fmaf(a1.y, w2, pu[5]);
            pu[6] = fmaf(s1.z, w1, pu[6]); pu[6] = fmaf(a1.z, w2, pu[6]);
            pu[7] = fmaf(s1.w, w1, pu[7]); pu[7] = fmaf(a1.w, w2, pu[7]);
        }
        float* pw = arena + dc * (HH * 9) + h * 9;
        #pragma unroll
        for (int r = 0; r < 8; ++r) pw[r] = pu[r];
    }
    __syncthreads();

    // combine B + LayerNorm + gelu. thread (h = t&255, rg = t>>8) rows {2rg, 2rg+1}.
    const int h = t & (HH - 1), rg = t >> 8;
    {
        float u0 = b_u1[h], u1 = u0;
        #pragma unroll
        for (int dc = 0; dc < 4; ++dc) {
            u0 += arena[dc * (HH * 9) + h * 9 + 2 * rg];
            u1 += arena[dc * (HH * 9) + h * 9 + 2 * rg + 1];
        }
        float s1a = u0, s2a = u0 * u0, s1b = u1, s2b = u1 * u1;
        #pragma unroll
        for (int o = 32; o > 0; o >>= 1) {
            s1a += __shfl_xor(s1a, o, 64);
            s2a += __shfl_xor(s2a, o, 64);
            s1b += __shfl_xor(s1b, o, 64);
            s2b += __shfl_xor(s2b, o, 64);
        }
        if ((t & 63) == 0) red[rg][(t >> 6) & 3] = make_float4(s1a, s2a, s1b, s2b);
        __syncthreads();
        const float4 r0 = red[rg][0], r1 = red[rg][1], r2 = red[rg][2], r3 = red[rg][3];
        const float lgv = ln_g[h], lbv = ln_b[h];
        const float t1a = r0.x + r1.x + r2.x + r3.x;
        const float t2a = r0.y + r1.y + r2.y + r3.y;
        const float t1b = r0.z + r1.z + r2.z + r3.z;
        const float t2b = r0.w + r1.w + r2.w + r3.w;
        const float mu0 = t1a * (1.0f / HH);
        const float var0 = t2a * (1.0f / HH) - mu0 * mu0;
        const float mu1 = t1b * (1.0f / HH);
        const float var1 = t2b * (1.0f / HH) - mu1 * mu1;
        ul[h][2 * rg]     = 0.5f * gelu2((u0 - mu0) * rsqrtf(var0 + LN_EPS) * lgv + lbv);
        ul[h][2 * rg + 1] = 0.5f * gelu2((u1 - mu1) * rsqrtf(var1 + LN_EPS) * lgv + lbv);
    }
    __syncthreads();

    // Phase D: partial out over hh-chunk. thread (d = t&127, hc = t>>7), 32 hh each.
    {
        const int d = t & (DD - 1), hc = t >> 7;
        float pd[8] = {0, 0, 0, 0, 0, 0, 0, 0};
        const float* __restrict__ W = W_u2 + d;
        const int hh0 = hc * 32;
        #pragma unroll 4
        for (int hh = hh0; hh < hh0 + 32; ++hh) {
            const float w = W[hh * DD];
            const float2 u01 = *(const float2*)&ul[hh][0];   // broadcast b64 x4
            const float2 u23 = *(const float2*)&ul[hh][2];
            const float2 u45 = *(const float2*)&ul[hh][4];
            const float2 u67 = *(const float2*)&ul[hh][6];
            pd[0] = fmaf(u01.x, w, pd[0]); pd[1] = fmaf(u01.y, w, pd[1]);
            pd[2] = fmaf(u23.x, w, pd[2]); pd[3] = fmaf(u23.y, w, pd[3]);
            pd[4] = fmaf(u45.x, w, pd[4]); pd[5] = fmaf(u45.y, w, pd[5]);
            pd[6] = fmaf(u67.x, w, pd[6]); pd[7] = fmaf(u67.y, w, pd[7]);
        }
        float* pw = arena + hc * (DD * 9) + d * 9;
        #pragma unroll
        for (int r = 0; r < 8; ++r) pw[r] = pd[r];
    }
    __syncthreads();
    {   // combine D: thread (d = t&127, r = t>>7)
        const int d = t & (DD - 1), r = t >> 7;
        float acc = b_u2[d];
        #pragma unroll
        for (int hc = 0; hc < 8; ++hc) acc += arena[hc * (DD * 9) + d * 9 + r];
        out[(row0 + r) * DD + d] = sl[d][r] + acc;
    }
}

extern "C" void kernel_launch(void* const* d_in, const int* in_sizes, int n_in,
                              void* d_out, int out_size, void* d_ws, size_t ws_size,
                              hipStream_t stream) {
    const float* slots = (const float*)d_in[0];
    const float* adj   = (const float*)d_in[1];
    const float* W_m1  = (const float*)d_in[2];
    const float* b_m1  = (const float*)d_in[3];
    const float* W_m2  = (const float*)d_in[4];
    const float* b_m2  = (const float*)d_in[5];
    const float* W_u1  = (const float*)d_in[6];
    const float* b_u1  = (const float*)d_in[7];
    const float* ln_g  = (const float*)d_in[8];
    const float* ln_b  = (const float*)d_in[9];
    const float* W_u2  = (const float*)d_in[10];
    const float* b_u2  = (const float*)d_in[11];
    float* out = (float*)d_out;
    float* ws  = (float*)d_ws;

    const int rows = BB * NN;            // 2048
    float* hi   = ws;
    float* hj   = hi + (size_t)rows * HH;
    float* g    = hj + (size_t)rows * HH;
    float* asum = g  + (size_t)rows * HH;

    hipLaunchKernelGGL(k_proj_m1, dim3(rows / 4), dim3(512), 0, stream,
                       slots, W_m1, b_m1, hi, hj);
    hipLaunchKernelGGL(k_msg_agg, dim3(rows), dim3(256), 0, stream,
                       adj, hi, hj, g, asum);
    hipLaunchKernelGGL(k_update, dim3(rows / 8), dim3(1024), 0, stream,
                       slots, g, asum, W_m2, b_m2, W_u1, b_u1,
                       ln_g, ln_b, W_u2, b_u2, out);
}

// Round 6
// 79.454 us; speedup vs baseline: 1.9473x; 1.0294x over previous
//
#include <hip/hip_runtime.h>
#include <math.h>

#define BB 8
#define NN 256
#define DD 128
#define HH 256
#define LN_EPS 1e-5f

// gelu2(x) = 2*gelu(x) = x + |x|*erf(|x|/sqrt2), branch-free A-S 7.1.26 erf.
// (fold the 0.5 into the consumer's scale factor)
__device__ __forceinline__ float gelu2(float x) {
    const float x2 = x * x;
    const float q  = fmaf(fabsf(x), 0.23164429f, 1.0f);      // 1 + p*|x|/sqrt2
    const float tt = __builtin_amdgcn_rcpf(q);
    const float e  = __builtin_amdgcn_exp2f(x2 * -0.72134752f); // exp(-x^2/2)
    float p = fmaf(tt, 1.061405429f, -1.453152027f);
    p = fmaf(tt, p, 1.421413741f);
    p = fmaf(tt, p, -0.284496736f);
    p = fmaf(tt, p, 0.254829592f);
    const float erf_abs = fmaf(-p * tt, e, 1.0f);
    return fmaf(fabsf(x), erf_abs, x);
}

// Kernel 1: hi = slots @ W_m1[:D] + b_m1 ; hj = slots @ W_m1[D:]
// 4 rows/block, 512 threads (h = t&255, half = t>>8), 512 blocks.
__global__ __launch_bounds__(512, 8) void k_proj_m1(
    const float* __restrict__ slots, const float* __restrict__ W_m1,
    const float* __restrict__ b_m1, float* __restrict__ hi, float* __restrict__ hj)
{
    __shared__ __align__(16) float s[DD][4];
    const int t = threadIdx.x;
    const int h = t & (HH - 1);
    const int half = t >> 8;
    const int row0 = blockIdx.x * 4;
    {   // 512 threads stage 4*128 floats exactly
        const int r = t & 3, d = t >> 2;
        s[d][r] = slots[(row0 + r) * DD + d];
    }
    __syncthreads();
    const float init = half ? 0.0f : b_m1[h];
    float a0 = init, a1 = init, a2 = init, a3 = init;
    const float* __restrict__ W = W_m1 + half * DD * HH + h;
    #pragma unroll 4
    for (int d = 0; d < DD; ++d) {
        const float w = W[d * HH];
        const float4 sv = *(const float4*)&s[d][0];   // broadcast
        a0 = fmaf(sv.x, w, a0);
        a1 = fmaf(sv.y, w, a1);
        a2 = fmaf(sv.z, w, a2);
        a3 = fmaf(sv.w, w, a3);
    }
    float* __restrict__ dst = half ? hj : hi;
    dst[(row0 + 0) * HH + h] = a0;
    dst[(row0 + 1) * HH + h] = a1;
    dst[(row0 + 2) * HH + h] = a2;
    dst[(row0 + 3) * HH + h] = a3;
}

// Kernel 2 (hot): g[b,i,h] = sum_j A[b,i,j]*gelu(hi[b,i,h]+hj[b,j,h]); asum = sum_j A
// 1 row per block, 2048 blocks x 256 threads.
// Thread = (jq = wave = t>>6, h0 = (t&63)*4).
// A-row read via SGPR s_load (wave-uniform addr by readfirstlane); hj via b128
// with a 2-j-deep software pipeline (prefetch distance ~340cy > L2 latency).
__global__ __launch_bounds__(256, 8) void k_msg_agg(
    const float* __restrict__ adj, const float* __restrict__ hi,
    const float* __restrict__ hj, float* __restrict__ g, float* __restrict__ asum)
{
    __shared__ __align__(16) float pg[3][HH];   // 3KB partials from jq=1..3
    const int t = threadIdx.x;
    const int row = blockIdx.x;
    const int b = row >> 8;
    const int jq = t >> 6;                      // == wave id
    const int h0 = (t & 63) * 4;

    if (t < 64) {                               // wave 0: raw adjacency row sum
        const float* __restrict__ ar = adj + (size_t)row * NN;
        float s1 = ar[t] + ar[t + 64] + ar[t + 128] + ar[t + 192];
        #pragma unroll
        for (int o = 32; o > 0; o >>= 1) s1 += __shfl_down(s1, o, 64);
        if (t == 0) asum[row] = s1;
    }

    // Wave-uniform A pointer -> scalar (s_load) reads, co-issue with VALU.
    const int jbase = __builtin_amdgcn_readfirstlane(jq * 64);
    const float* __restrict__ Aq = adj + (size_t)row * NN + jbase;
    const float4 hv = *(const float4*)(hi + (size_t)row * HH + h0);
    const float* __restrict__ hjp = hj + ((size_t)b * NN + jbase) * HH + h0;

    float a0 = 0.0f, a1 = 0.0f, a2 = 0.0f, a3 = 0.0f;
    float4 c0 = *(const float4*)(hjp);
    float4 c1 = *(const float4*)(hjp + HH);
    #pragma unroll 4
    for (int jj = 0; jj < 62; jj += 2) {
        const float4 n0 = *(const float4*)(hjp + (size_t)(jj + 2) * HH);
        const float4 n1 = *(const float4*)(hjp + (size_t)(jj + 3) * HH);
        const float A0 = Aq[jj];
        const float A1 = Aq[jj + 1];
        a0 = fmaf(A0, gelu2(hv.x + c0.x), a0);
        a1 = fmaf(A0, gelu2(hv.y + c0.y), a1);
        a2 = fmaf(A0, gelu2(hv.z + c0.z), a2);
        a3 = fmaf(A0, gelu2(hv.w + c0.w), a3);
        a0 = fmaf(A1, gelu2(hv.x + c1.x), a0);
        a1 = fmaf(A1, gelu2(hv.y + c1.y), a1);
        a2 = fmaf(A1, gelu2(hv.z + c1.z), a2);
        a3 = fmaf(A1, gelu2(hv.w + c1.w), a3);
        c0 = n0; c1 = n1;
    }
    {   // tail: j = 62, 63
        const float A0 = Aq[62];
        const float A1 = Aq[63];
        a0 = fmaf(A0, gelu2(hv.x + c0.x), a0);
        a1 = fmaf(A0, gelu2(hv.y + c0.y), a1);
        a2 = fmaf(A0, gelu2(hv.z + c0.z), a2);
        a3 = fmaf(A0, gelu2(hv.w + c0.w), a3);
        a0 = fmaf(A1, gelu2(hv.x + c1.x), a0);
        a1 = fmaf(A1, gelu2(hv.y + c1.y), a1);
        a2 = fmaf(A1, gelu2(hv.z + c1.z), a2);
        a3 = fmaf(A1, gelu2(hv.w + c1.w), a3);
    }

    if (jq) *(float4*)&pg[jq - 1][h0] = make_float4(a0, a1, a2, a3);
    __syncthreads();
    if (!jq) {
        const float4 p0 = *(const float4*)&pg[0][h0];
        const float4 p1 = *(const float4*)&pg[1][h0];
        const float4 p2 = *(const float4*)&pg[2][h0];
        *(float4*)(g + (size_t)row * HH + h0) =
            make_float4(0.5f * (a0 + p0.x + p1.x + p2.x),
                        0.5f * (a1 + p0.y + p1.y + p2.y),
                        0.5f * (a2 + p0.z + p1.z + p2.z),
                        0.5f * (a3 + p0.w + p1.w + p2.w));
    }
}

// Kernel 3: ag = g@W_m2 + asum*b_m2 ; u = sl@W_u1[:D] + ag@W_u1[D:] + b_u1
//           u = gelu(LN(u)) ; out = slots + u@W_u2 + b_u2
// 8 rows/block, 1024 threads, 256 blocks. Each matmul phase is chunked so
// every W element is loaded exactly ONCE per block (partials in LDS arena).
__global__ __launch_bounds__(1024, 8) void k_update(
    const float* __restrict__ slots, const float* __restrict__ g,
    const float* __restrict__ asum,
    const float* __restrict__ W_m2, const float* __restrict__ b_m2,
    const float* __restrict__ W_u1, const float* __restrict__ b_u1,
    const float* __restrict__ ln_g, const float* __restrict__ ln_b,
    const float* __restrict__ W_u2, const float* __restrict__ b_u2,
    float* __restrict__ out)
{
    __shared__ __align__(16) float gl[HH][8];   // 8KB  gl[h][r]
    __shared__ __align__(16) float sl[DD][8];   // 4KB
    __shared__ __align__(16) float ag[DD][8];   // 4KB
    __shared__ __align__(16) float ul[HH][10];  // 10KB, stride 10 (b64-aligned rows)
    __shared__ float4 red[4][4];
    __shared__ float arena[9216];               // 36KB: pA[8][128][9] / pB[4][256][9]
    const int t = threadIdx.x;
    const int row0 = blockIdx.x * 8;

    for (int k = t; k < 8 * HH; k += 1024) {
        const int r = k & 7, hh = k >> 3;
        gl[hh][r] = g[(row0 + r) * HH + hh];
    }
    for (int k = t; k < 8 * DD; k += 1024) {
        const int r = k & 7, d = k >> 3;
        sl[d][r] = slots[(row0 + r) * DD + d];
    }
    __syncthreads();

    // Phase A: partial ag over hh-chunk. thread (d = t&127, hc = t>>7), 32 hh each.
    {
        const int d = t & (DD - 1), hc = t >> 7;
        float pa[8] = {0, 0, 0, 0, 0, 0, 0, 0};
        const float* __restrict__ W = W_m2 + d;
        const int hh0 = hc * 32;
        #pragma unroll 4
        for (int hh = hh0; hh < hh0 + 32; ++hh) {
            const float w = W[hh * DD];
            const float4 g0 = *(const float4*)&gl[hh][0];   // broadcast
            const float4 g1 = *(const float4*)&gl[hh][4];
            pa[0] = fmaf(g0.x, w, pa[0]); pa[1] = fmaf(g0.y, w, pa[1]);
            pa[2] = fmaf(g0.z, w, pa[2]); pa[3] = fmaf(g0.w, w, pa[3]);
            pa[4] = fmaf(g1.x, w, pa[4]); pa[5] = fmaf(g1.y, w, pa[5]);
            pa[6] = fmaf(g1.z, w, pa[6]); pa[7] = fmaf(g1.w, w, pa[7]);
        }
        float* pw = arena + hc * (DD * 9) + d * 9;
        #pragma unroll
        for (int r = 0; r < 8; ++r) pw[r] = pa[r];
    }
    __syncthreads();
    {   // combine A: thread (d = t&127, r = t>>7)
        const int d = t & (DD - 1), r = t >> 7;
        float acc = asum[row0 + r] * b_m2[d];
        #pragma unroll
        for (int hc = 0; hc < 8; ++hc) acc += arena[hc * (DD * 9) + d * 9 + r];
        ag[d][r] = acc;
    }
    __syncthreads();

    // Phase B: partial u over d-chunk. thread (h = t&255, dc = t>>8), 32 d each.
    {
        const int h = t & (HH - 1), dc = t >> 8;
        float pu[8] = {0, 0, 0, 0, 0, 0, 0, 0};
        const float* __restrict__ W1 = W_u1 + h;
        const float* __restrict__ W2 = W_u1 + DD * HH + h;
        const int d0 = dc * 32;
        #pragma unroll 2
        for (int d = d0; d < d0 + 32; ++d) {
            const float w1 = W1[d * HH];
            const float w2 = W2[d * HH];
            const float4 s0 = *(const float4*)&sl[d][0];
            const float4 s1 = *(const float4*)&sl[d][4];
            const float4 a0 = *(const float4*)&ag[d][0];
            const float4 a1 = *(const float4*)&ag[d][4];
            pu[0] = fmaf(s0.x, w1, pu[0]); pu[0] = fmaf(a0.x, w2, pu[0]);
            pu[1] = fmaf(s0.y, w1, pu[1]); pu[1] = fmaf(a0.y, w2, pu[1]);
            pu[2] = fmaf(s0.z, w1, pu[2]); pu[2] = fmaf(a0.z, w2, pu[2]);
            pu[3] = fmaf(s0.w, w1, pu[3]); pu[3] = fmaf(a0.w, w2, pu[3]);
            pu[4] = fmaf(s1.x, w1, pu[4]); pu[4] = fmaf(a1.x, w2, pu[4]);
            pu[5] = fmaf(s1.y, w1, pu[5]); pu[5] = fmaf(a1.y, w2, pu[5]);
            pu[6] = fmaf(s1.z, w1, pu[6]); pu[6] = fmaf(a1.z, w2, pu[6]);
            pu[7] = fmaf(s1.w, w1, pu[7]); pu[7] = fmaf(a1.w, w2, pu[7]);
        }
        float* pw = arena + dc * (HH * 9) + h * 9;
        #pragma unroll
        for (int r = 0; r < 8; ++r) pw[r] = pu[r];
    }
    __syncthreads();

    // combine B + LayerNorm + gelu. thread (h = t&255, rg = t>>8) rows {2rg, 2rg+1}.
    const int h = t & (HH - 1), rg = t >> 8;
    {
        float u0 = b_u1[h], u1 = u0;
        #pragma unroll
        for (int dc = 0; dc < 4; ++dc) {
            u0 += arena[dc * (HH * 9) + h * 9 + 2 * rg];
            u1 += arena[dc * (HH * 9) + h * 9 + 2 * rg + 1];
        }
        float s1a = u0, s2a = u0 * u0, s1b = u1, s2b = u1 * u1;
        #pragma unroll
        for (int o = 32; o > 0; o >>= 1) {
            s1a += __shfl_xor(s1a, o, 64);
            s2a += __shfl_xor(s2a, o, 64);
            s1b += __shfl_xor(s1b, o, 64);
            s2b += __shfl_xor(s2b, o, 64);
        }
        if ((t & 63) == 0) red[rg][(t >> 6) & 3] = make_float4(s1a, s2a, s1b, s2b);
        __syncthreads();
        const float4 r0 = red[rg][0], r1 = red[rg][1], r2 = red[rg][2], r3 = red[rg][3];
        const float lgv = ln_g[h], lbv = ln_b[h];
        const float t1a = r0.x + r1.x + r2.x + r3.x;
        const float t2a = r0.y + r1.y + r2.y + r3.y;
        const float t1b = r0.z + r1.z + r2.z + r3.z;
        const float t2b = r0.w + r1.w + r2.w + r3.w;
        const float mu0 = t1a * (1.0f / HH);
        const float var0 = t2a * (1.0f / HH) - mu0 * mu0;
        const float mu1 = t1b * (1.0f / HH);
        const float var1 = t2b * (1.0f / HH) - mu1 * mu1;
        ul[h][2 * rg]     = 0.5f * gelu2((u0 - mu0) * rsqrtf(var0 + LN_EPS) * lgv + lbv);
        ul[h][2 * rg + 1] = 0.5f * gelu2((u1 - mu1) * rsqrtf(var1 + LN_EPS) * lgv + lbv);
    }
    __syncthreads();

    // Phase D: partial out over hh-chunk. thread (d = t&127, hc = t>>7), 32 hh each.
    {
        const int d = t & (DD - 1), hc = t >> 7;
        float pd[8] = {0, 0, 0, 0, 0, 0, 0, 0};
        const float* __restrict__ W = W_u2 + d;
        const int hh0 = hc * 32;
        #pragma unroll 4
        for (int hh = hh0; hh < hh0 + 32; ++hh) {
            const float w = W[hh * DD];
            const float2 u01 = *(const float2*)&ul[hh][0];   // broadcast b64 x4
            const float2 u23 = *(const float2*)&ul[hh][2];
            const float2 u45 = *(const float2*)&ul[hh][4];
            const float2 u67 = *(const float2*)&ul[hh][6];
            pd[0] = fmaf(u01.x, w, pd[0]); pd[1] = fmaf(u01.y, w, pd[1]);
            pd[2] = fmaf(u23.x, w, pd[2]); pd[3] = fmaf(u23.y, w, pd[3]);
            pd[4] = fmaf(u45.x, w, pd[4]); pd[5] = fmaf(u45.y, w, pd[5]);
            pd[6] = fmaf(u67.x, w, pd[6]); pd[7] = fmaf(u67.y, w, pd[7]);
        }
        float* pw = arena + hc * (DD * 9) + d * 9;
        #pragma unroll
        for (int r = 0; r < 8; ++r) pw[r] = pd[r];
    }
    __syncthreads();
    {   // combine D: thread (d = t&127, r = t>>7)
        const int d = t & (DD - 1), r = t >> 7;
        float acc = b_u2[d];
        #pragma unroll
        for (int hc = 0; hc < 8; ++hc) acc += arena[hc * (DD * 9) + d * 9 + r];
        out[(row0 + r) * DD + d] = sl[d][r] + acc;
    }
}

extern "C" void kernel_launch(void* const* d_in, const int* in_sizes, int n_in,
                              void* d_out, int out_size, void* d_ws, size_t ws_size,
                              hipStream_t stream) {
    const float* slots = (const float*)d_in[0];
    const float* adj   = (const float*)d_in[1];
    const float* W_m1  = (const float*)d_in[2];
    const float* b_m1  = (const float*)d_in[3];
    const float* W_m2  = (const float*)d_in[4];
    const float* b_m2  = (const float*)d_in[5];
    const float* W_u1  = (const float*)d_in[6];
    const float* b_u1  = (const float*)d_in[7];
    const float* ln_g  = (const float*)d_in[8];
    const float* ln_b  = (const float*)d_in[9];
    const float* W_u2  = (const float*)d_in[10];
    const float* b_u2  = (const float*)d_in[11];
    float* out = (float*)d_out;
    float* ws  = (float*)d_ws;

    const int rows = BB * NN;            // 2048
    float* hi   = ws;
    float* hj   = hi + (size_t)rows * HH;
    float* g    = hj + (size_t)rows * HH;
    float* asum = g  + (size_t)rows * HH;

    hipLaunchKernelGGL(k_proj_m1, dim3(rows / 4), dim3(512), 0, stream,
                       slots, W_m1, b_m1, hi, hj);
    hipLaunchKernelGGL(k_msg_agg, dim3(rows), dim3(256), 0, stream,
                       adj, hi, hj, g, asum);
    hipLaunchKernelGGL(k_update, dim3(rows / 8), dim3(1024), 0, stream,
                       slots, g, asum, W_m2, b_m2, W_u1, b_u1,
                       ln_g, ln_b, W_u2, b_u2, out);
}